// Round 1
// baseline (6938.844 us; speedup 1.0000x reference)
//
#include <hip/hip_runtime.h>

#define TMAX 8192
#define H 128

__device__ __forceinline__ float sigf(float x)   { return 1.f / (1.f + __expf(-x)); }
__device__ __forceinline__ float tanhf_fast(float x) { return 2.f / (1.f + __expf(-2.f * x)) - 1.f; }

// One block, 512 threads (8 waves). Thread j owns gate-row j (W_hh row in VGPRs).
// h lives in LDS and is broadcast-read; 2 barriers per timestep.
__global__ __launch_bounds__(512, 2)
void lstm_seq_kernel(const float* __restrict__ x,
                     const float* __restrict__ Wih,
                     const float* __restrict__ Whh,
                     const float* __restrict__ bih,
                     const float* __restrict__ bhh,
                     const float* __restrict__ Wlin,
                     const float* __restrict__ blin,
                     const float* __restrict__ h0,
                     const float* __restrict__ c0,
                     float* __restrict__ out,
                     int T)
{
    __shared__ float  x_s[TMAX];
    __shared__ float4 h_s4[H / 4];       // h broadcast buffer
    __shared__ float  gates_s[4 * H];    // pre-activation gates i|f|g|o

    const int j = threadIdx.x;  // 0..511 = gate-row index

    // Stage input sequence into LDS (one-time, coalesced).
    for (int idx = j; idx < T; idx += 512) x_s[idx] = x[idx];

    // Pull this thread's W_hh row into registers (32 x float4 = 128 VGPRs).
    float4 w[32];
    const float4* wrow = (const float4*)(Whh + j * H);
    #pragma unroll
    for (int kk = 0; kk < 32; ++kk) w[kk] = wrow[kk];

    const float wih  = Wih[j];
    const float bsum = bih[j] + bhh[j];

    float c = 0.f;
    if (j < H) {
        c = c0[j];
        ((float*)h_s4)[j] = h0[j];
    }
    __syncthreads();

    for (int t = 0; t < T; ++t) {
        // gates[j] = x[t]*Wih[j] + bih[j] + bhh[j] + dot(Whh_row_j, h)
        float acc = fmaf(x_s[t], wih, bsum);
        float a0 = 0.f, a1 = 0.f, a2 = 0.f, a3 = 0.f;
        #pragma unroll
        for (int kk = 0; kk < 32; ++kk) {
            const float4 h4 = h_s4[kk];   // same address across lanes -> LDS broadcast
            a0 = fmaf(w[kk].x, h4.x, a0);
            a1 = fmaf(w[kk].y, h4.y, a1);
            a2 = fmaf(w[kk].z, h4.z, a2);
            a3 = fmaf(w[kk].w, h4.w, a3);
        }
        gates_s[j] = acc + ((a0 + a2) + (a1 + a3));
        __syncthreads();

        if (j < H) {
            const float gi = gates_s[j];
            const float gf = gates_s[j + H];
            const float gg = gates_s[j + 2 * H];
            const float go = gates_s[j + 3 * H];
            const float ig = sigf(gi);
            const float fg = sigf(gf);
            const float gg2 = tanhf_fast(gg);
            const float og = sigf(go);
            c = fmaf(fg, c, ig * gg2);
            const float hval = og * tanhf_fast(c);
            ((float*)h_s4)[j] = hval;
        }
        __syncthreads();
    }

    // Final linear: out = dot(W_lin, h_T) + b_lin  (wave 0 only)
    if (j < 64) {
        const float* hs = (const float*)h_s4;
        float v = Wlin[j] * hs[j] + Wlin[j + 64] * hs[j + 64];
        #pragma unroll
        for (int off = 32; off >= 1; off >>= 1) v += __shfl_down(v, off);
        if (j == 0) out[0] = v + blin[0];
    }
}

extern "C" void kernel_launch(void* const* d_in, const int* in_sizes, int n_in,
                              void* d_out, int out_size, void* d_ws, size_t ws_size,
                              hipStream_t stream) {
    const float* x    = (const float*)d_in[0];
    const float* Wih  = (const float*)d_in[1];
    const float* Whh  = (const float*)d_in[2];
    const float* bih  = (const float*)d_in[3];
    const float* bhh  = (const float*)d_in[4];
    const float* Wlin = (const float*)d_in[5];
    const float* blin = (const float*)d_in[6];
    const float* h0   = (const float*)d_in[7];
    const float* c0   = (const float*)d_in[8];
    float* out = (float*)d_out;
    const int T = in_sizes[0];

    lstm_seq_kernel<<<1, 512, 0, stream>>>(x, Wih, Whh, bih, bhh, Wlin, blin,
                                           h0, c0, out, T);
}

// Round 2
// 5804.904 us; speedup vs baseline: 1.1953x; 1.1953x over previous
//
#include <hip/hip_runtime.h>

#define TMAX 8192
#define H 128

__device__ __forceinline__ float sigf(float x)       { return 1.f / (1.f + __expf(-x)); }
__device__ __forceinline__ float tanhf_fast(float x) { return 2.f / (1.f + __expf(-2.f * x)) - 1.f; }

// One block, 1024 threads (16 waves, 4/SIMD).
// Thread t: k-quarter q = t>>8 (wave-uniform), rows r0 = t&255 and r1 = r0+256.
// 64 weight floats/thread -> stays in VGPRs under the 128-VGPR cap.
// Per step: 8 broadcast ds_read_b128 of h feed 64 FMAs; partials to LDS;
// 128 activation threads sum 4 quarters, update c/h.
__global__ __launch_bounds__(1024, 4)
void lstm_seq_kernel(const float* __restrict__ x,
                     const float* __restrict__ Wih,
                     const float* __restrict__ Whh,
                     const float* __restrict__ bih,
                     const float* __restrict__ bhh,
                     const float* __restrict__ Wlin,
                     const float* __restrict__ blin,
                     const float* __restrict__ h0,
                     const float* __restrict__ c0,
                     float* __restrict__ out,
                     int T)
{
    __shared__ float  x_s[TMAX];        // 32 KB
    __shared__ float4 h_s4[H / 4];      // h broadcast buffer (512 B)
    __shared__ float  part[4 * 512];    // per-quarter partial dots (8 KB)

    const int t  = threadIdx.x;         // 0..1023
    const int q  = t >> 8;              // k-quarter 0..3 (wave-uniform)
    const int r0 = t & 255;             // first row
    const int r1 = r0 + 256;            // second row

    // Stage input sequence into LDS (one-time, coalesced).
    for (int idx = t; idx < T; idx += 1024) x_s[idx] = x[idx];

    // Weights for (r0,q) and (r1,q): 8+8 float4 = 64 VGPRs.
    float4 wA[8], wB[8];
    {
        const float4* a = (const float4*)(Whh + r0 * H + q * 32);
        const float4* b = (const float4*)(Whh + r1 * H + q * 32);
        #pragma unroll
        for (int i = 0; i < 8; ++i) { wA[i] = a[i]; wB[i] = b[i]; }
    }

    // x-weight and bias folded into quarter 0's partial (q==0 is wave-uniform).
    float wihA = 0.f, wihB = 0.f, bsA = 0.f, bsB = 0.f;
    if (q == 0) {
        wihA = Wih[r0];  bsA = bih[r0] + bhh[r0];
        wihB = Wih[r1];  bsB = bih[r1] + bhh[r1];
    }

    float c = 0.f;
    if (t < H) {
        c = c0[t];
        ((float*)h_s4)[t] = h0[t];
    }
    __syncthreads();

    const int hbase = q * 8;            // float4 index into h for this quarter

    for (int step = 0; step < T; ++step) {
        float a0 = 0.f, a1 = 0.f, b0 = 0.f, b1 = 0.f;
        #pragma unroll
        for (int i = 0; i < 8; ++i) {
            const float4 h4 = h_s4[hbase + i];   // same addr across wave -> broadcast
            a0 = fmaf(wA[i].x, h4.x, a0);
            a1 = fmaf(wA[i].y, h4.y, a1);
            a0 = fmaf(wA[i].z, h4.z, a0);
            a1 = fmaf(wA[i].w, h4.w, a1);
            b0 = fmaf(wB[i].x, h4.x, b0);
            b1 = fmaf(wB[i].y, h4.y, b1);
            b0 = fmaf(wB[i].z, h4.z, b0);
            b1 = fmaf(wB[i].w, h4.w, b1);
        }
        float accA = a0 + a1;
        float accB = b0 + b1;
        if (q == 0) {
            const float xv = x_s[step];
            accA += fmaf(xv, wihA, bsA);
            accB += fmaf(xv, wihB, bsB);
        }
        part[q * 512 + r0] = accA;      // stride-1 per wave: conflict-free
        part[q * 512 + r1] = accB;
        __syncthreads();

        if (t < H) {
            // gates: i = rows 0..127, f = 128..255, g = 256..383, o = 384..511
            float gi = 0.f, gf = 0.f, gg = 0.f, go = 0.f;
            #pragma unroll
            for (int qq = 0; qq < 4; ++qq) {
                const float* p = part + qq * 512;
                gi += p[t];
                gf += p[t + 128];
                gg += p[t + 256];
                go += p[t + 384];
            }
            const float ig  = sigf(gi);
            const float fg  = sigf(gf);
            const float gg2 = tanhf_fast(gg);
            const float og  = sigf(go);
            c = fmaf(fg, c, ig * gg2);
            ((float*)h_s4)[t] = og * tanhf_fast(c);
        }
        __syncthreads();
    }

    // Final linear: out = dot(W_lin, h_T) + b_lin  (wave 0 only)
    if (t < 64) {
        const float* hs = (const float*)h_s4;
        float v = Wlin[t] * hs[t] + Wlin[t + 64] * hs[t + 64];
        #pragma unroll
        for (int off = 32; off >= 1; off >>= 1) v += __shfl_down(v, off);
        if (t == 0) out[0] = v + blin[0];
    }
}

extern "C" void kernel_launch(void* const* d_in, const int* in_sizes, int n_in,
                              void* d_out, int out_size, void* d_ws, size_t ws_size,
                              hipStream_t stream) {
    const float* x    = (const float*)d_in[0];
    const float* Wih  = (const float*)d_in[1];
    const float* Whh  = (const float*)d_in[2];
    const float* bih  = (const float*)d_in[3];
    const float* bhh  = (const float*)d_in[4];
    const float* Wlin = (const float*)d_in[5];
    const float* blin = (const float*)d_in[6];
    const float* h0   = (const float*)d_in[7];
    const float* c0   = (const float*)d_in[8];
    float* out = (float*)d_out;
    const int T = in_sizes[0];

    lstm_seq_kernel<<<1, 1024, 0, stream>>>(x, Wih, Whh, bih, bhh, Wlin, blin,
                                            h0, c0, out, T);
}